// Round 3
// baseline (48.797 us; speedup 1.0000x reference)
//
#include <hip/hip_runtime.h>
#include <math.h>

// Problem constants (from setup_inputs)
#define B_  16
#define A_  3
#define H_  76
#define W_  76
#define C_  80
#define T_  32
#define CELLS (B_*A_*H_*W_)      // 277248
#define GS_ 240                  // streaming (noobj) blocks
#define GT_ 16                   // target blocks, one per image
#define IGNORE_THRES_ 0.5f
#define EPS_BCE_ 1e-7f

__device__ __forceinline__ float sigmoidf_(float z) { return 1.0f / (1.0f + expf(-z)); }
__device__ __forceinline__ float smooth_l1_(float d) {
    d = fabsf(d);
    return (d < 1.0f) ? 0.5f * d * d : d - 0.5f;
}
__device__ __forceinline__ float noobj_term_(float z) {
    float pc = sigmoidf_(z);
    pc = fminf(fmaxf(pc, EPS_BCE_), 1.0f - EPS_BCE_);
    return -logf(1.0f - pc);
}

// ---------------------------------------------------------------------------
// Kernel A: 256 blocks x 256 threads, block-specialized.
//   blocks [0,240): grid-stride unconditional noobj BCE sum -> pn[blk]
//   blocks [240,256): image b = blk-240; 4 waves x 8 targets each:
//     - wave-parallel class-row (coalesced loads, butterfly argmax/sumexp)
//     - winner detection (last-write-wins) via LDS keys of the image's 32 tgts
//     - flagged-cell dedup (<=96 pairs) -> subtraction terms for noobj
//     - per-image acc[10] -> iacc
// iacc per image: [0..3]=lx,ly,lw,lh [4]=obj [5]=ce [6]=nM [7]=ncor
//                 [8]=sub_term [9]=sub_count
// ---------------------------------------------------------------------------
__global__ __launch_bounds__(256) void kmain(
    const float* __restrict__ xreg, const float* __restrict__ xcls,
    const float* __restrict__ tgt, const float* __restrict__ anch,
    float* __restrict__ pn, float* __restrict__ iacc)
{
    const int blk = blockIdx.x, tid = threadIdx.x;
    const int lane = tid & 63, wv = tid >> 6;

    if (blk < GS_) {
        // ---- streaming noobj total ----
        float s = 0.0f;
        for (int i = blk * 256 + tid; i < CELLS; i += GS_ * 256)
            s += noobj_term_(xreg[(size_t)i * 5 + 4]);
        #pragma unroll
        for (int off = 32; off > 0; off >>= 1) s += __shfl_down(s, off, 64);
        __shared__ float sw[4];
        if (lane == 0) sw[wv] = s;
        __syncthreads();
        if (tid == 0) pn[blk] = sw[0] + sw[1] + sw[2] + sw[3];
        return;
    }

    // ---- target block for image b ----
    const int b = blk - GS_;
    __shared__ int s_key[T_];
    __shared__ int s_cell[T_ * A_];
    __shared__ unsigned char s_flag[T_ * A_];
    __shared__ float s_red[4 * 10];

    const float aw0 = anch[0], ah0 = anch[1];
    const float aw1 = anch[2], ah1 = anch[3];
    const float aw2 = anch[4], ah2 = anch[5];

    // phase 1: per-target keys + flagged (anchor,cell) pairs
    if (tid < T_) {
        const float* tp = tgt + (size_t)(b * T_ + tid) * 5;
        float gx = tp[0] * (float)W_, gy = tp[1] * (float)H_;
        float gw = tp[2] * (float)W_, gh = tp[3] * (float)H_;
        int gi = min(max((int)floorf(gx), 0), W_ - 1);
        int gj = min(max((int)floorf(gy), 0), H_ - 1);
        float area = gw * gh;
        float i0 = fminf(gw, aw0) * fminf(gh, ah0);
        float iou0 = i0 / (area + aw0 * ah0 - i0 + 1e-16f);
        float i1 = fminf(gw, aw1) * fminf(gh, ah1);
        float iou1 = i1 / (area + aw1 * ah1 - i1 + 1e-16f);
        float i2 = fminf(gw, aw2) * fminf(gh, ah2);
        float iou2 = i2 / (area + aw2 * ah2 - i2 + 1e-16f);
        int best = 0; float bi = iou0;
        if (iou1 > bi) { best = 1; bi = iou1; }
        if (iou2 > bi) { best = 2; bi = iou2; }
        s_key[tid] = (best * H_ + gj) * W_ + gi;
        float ious[3] = { iou0, iou1, iou2 };
        #pragma unroll
        for (int a = 0; a < A_; ++a) {
            s_cell[tid * A_ + a] = (((b * A_ + a) * H_ + gj) * W_ + gi);
            s_flag[tid * A_ + a] = (a == best || ious[a] > IGNORE_THRES_) ? 1 : 0;
        }
    }
    __syncthreads();

    // phase 2: dedup flagged cells, gather subtraction terms
    float sub_t = 0.0f, sub_c = 0.0f;
    if (tid < T_ * A_ && s_flag[tid]) {
        int c = s_cell[tid];
        bool first = true;
        for (int q = 0; q < tid; ++q)
            if (s_flag[q] && s_cell[q] == c) { first = false; break; }
        if (first) {
            sub_t = noobj_term_(xreg[(size_t)c * 5 + 4]);
            sub_c = 1.0f;
        }
    }

    // phase 3: wave wv handles targets lt = wv*8 .. wv*8+7
    float alx = 0, aly = 0, alw = 0, alh = 0, aobj = 0, ace = 0, anm = 0, anc = 0;
    for (int k = 0; k < 8; ++k) {
        const int lt = wv * 8 + k;
        const float* tp = tgt + (size_t)(b * T_ + lt) * 5;
        float gx = tp[0] * (float)W_, gy = tp[1] * (float)H_;
        float gw = tp[2] * (float)W_, gh = tp[3] * (float)H_;
        int cls = (int)tp[4];
        int gi = min(max((int)floorf(gx), 0), W_ - 1);
        int gj = min(max((int)floorf(gy), 0), H_ - 1);
        float area = gw * gh;
        float i0 = fminf(gw, aw0) * fminf(gh, ah0);
        float iou0 = i0 / (area + aw0 * ah0 - i0 + 1e-16f);
        float i1 = fminf(gw, aw1) * fminf(gh, ah1);
        float iou1 = i1 / (area + aw1 * ah1 - i1 + 1e-16f);
        float i2 = fminf(gw, aw2) * fminf(gh, ah2);
        float iou2 = i2 / (area + aw2 * ah2 - i2 + 1e-16f);
        int best = 0; float bi = iou0;
        if (iou1 > bi) { best = 1; bi = iou1; }
        if (iou2 > bi) { best = 2; bi = iou2; }

        int cell = ((b * A_ + best) * H_ + gj) * W_ + gi;
        const float* rp = xreg + (size_t)cell * 5;
        float rc = rp[4];

        // wave-parallel class row: lane l holds classes l and 64+l
        const float* cp = xcls + (size_t)cell * C_;
        float v1 = cp[lane];
        float v2 = (lane < 16) ? cp[64 + lane] : -INFINITY;
        float bv; int bidx;
        if (v2 > v1) { bv = v2; bidx = 64 + lane; }
        else         { bv = v1; bidx = lane; }
        #pragma unroll
        for (int off = 1; off < 64; off <<= 1) {
            float ov = __shfl_xor(bv, off, 64);
            int   oi = __shfl_xor(bidx, off, 64);
            if (ov > bv || (ov == bv && oi < bidx)) { bv = ov; bidx = oi; }
        }
        float m = bv;
        float e = expf(v1 - m) + ((lane < 16) ? expf(v2 - m) : 0.0f);
        #pragma unroll
        for (int off = 1; off < 64; off <<= 1) e += __shfl_xor(e, off, 64);
        float lse = m + logf(e);
        float cpval = (cls < 64) ? __shfl(v1, cls, 64) : __shfl(v2, cls - 64, 64);

        // last-write-wins winner within the image
        bool winner = true;
        int mykey = s_key[lt];
        for (int u = lt + 1; u < T_; ++u)
            if (s_key[u] == mykey) { winner = false; break; }

        if (lane == 0) {
            if (bidx == cls && rc > 0.0f) anc += 1.0f;  // sigmoid(rc)>0.5
            if (winner) {
                float rx = rp[0], ry = rp[1], rw = rp[2], rh = rp[3];
                float aw = (best == 0) ? aw0 : ((best == 1) ? aw1 : aw2);
                float ah = (best == 0) ? ah0 : ((best == 1) ? ah1 : ah2);
                alx += smooth_l1_(sigmoidf_(rx) - (gx - (float)gi));
                aly += smooth_l1_(sigmoidf_(ry) - (gy - (float)gj));
                alw += smooth_l1_(rw - logf(gw / aw + 1e-16f));
                alh += smooth_l1_(rh - logf(gh / ah + 1e-16f));
                float pc = sigmoidf_(rc);
                pc = fminf(fmaxf(pc, EPS_BCE_), 1.0f - EPS_BCE_);
                aobj += -logf(pc);
                ace += lse - cpval;
                anm += 1.0f;
            }
        }
    }

    // block reduce 10 quantities (deterministic: wave tree + fixed wave order)
    float vals[10] = { alx, aly, alw, alh, aobj, ace, anm, anc, sub_t, sub_c };
    #pragma unroll
    for (int q = 0; q < 10; ++q) {
        float v = vals[q];
        #pragma unroll
        for (int off = 32; off > 0; off >>= 1) v += __shfl_down(v, off, 64);
        vals[q] = v;
    }
    if (lane == 0) {
        #pragma unroll
        for (int q = 0; q < 10; ++q) s_red[wv * 10 + q] = vals[q];
    }
    __syncthreads();
    if (tid == 0) {
        #pragma unroll
        for (int q = 0; q < 10; ++q) {
            float s = 0.0f;
            for (int w2 = 0; w2 < 4; ++w2) s += s_red[w2 * 10 + q];
            iacc[b * 10 + q] = s;
        }
    }
}

// ---------------------------------------------------------------------------
// Kernel B: 1 block, 64 threads — deterministic final combine.
// ---------------------------------------------------------------------------
__global__ __launch_bounds__(64) void kfinal(
    const float* __restrict__ pn, const float* __restrict__ iacc,
    float* __restrict__ out)
{
    int lane = threadIdx.x;
    float s = 0.0f;
    for (int i = lane; i < GS_; i += 64) s += pn[i];
    #pragma unroll
    for (int off = 1; off < 64; off <<= 1) s += __shfl_xor(s, off, 64);

    float a[10];
    #pragma unroll
    for (int q = 0; q < 10; ++q) {
        float v = (lane < GT_) ? iacc[lane * 10 + q] : 0.0f;
        #pragma unroll
        for (int off = 1; off < 64; off <<= 1) v += __shfl_xor(v, off, 64);
        a[q] = v;
    }

    if (lane == 0) {
        float noobj_sum = s - a[8];
        float nF = fmaxf((float)CELLS - a[9], 1.0f);
        float nM = fmaxf(a[6], 1.0f);
        float lx = a[0] / nM, ly = a[1] / nM;
        float lw = a[2] / nM, lh = a[3] / nM;
        float lconf = noobj_sum / nF + a[4] / nM;
        float lcls = a[5] / nM;
        float coord = lx + ly + lw + lh;
        out[0] = coord + lconf + lcls;
        out[1] = coord;
        out[2] = lconf;
        out[3] = lcls;
        out[4] = a[7];  // n_correct (float32 buffer)
    }
}

extern "C" void kernel_launch(void* const* d_in, const int* in_sizes, int n_in,
                              void* d_out, int out_size, void* d_ws, size_t ws_size,
                              hipStream_t stream) {
    const float* xreg = (const float*)d_in[0];
    const float* xcls = (const float*)d_in[1];
    const float* tgt  = (const float*)d_in[2];
    const float* anch = (const float*)d_in[3];
    float* out = (float*)d_out;

    char* ws = (char*)d_ws;
    float* pn   = (float*)ws;                 // GS_ floats
    float* iacc = (float*)(ws + GS_ * 4);     // GT_*10 floats

    kmain<<<GS_ + GT_, 256, 0, stream>>>(xreg, xcls, tgt, anch, pn, iacc);
    kfinal<<<1, 64, 0, stream>>>(pn, iacc, out);
}

// Round 4
// 48.219 us; speedup vs baseline: 1.0120x; 1.0120x over previous
//
#include <hip/hip_runtime.h>
#include <math.h>

// Problem constants (from setup_inputs)
#define B_  16
#define A_  3
#define H_  76
#define W_  76
#define C_  80
#define T_  32
#define CELLS (B_*A_*H_*W_)      // 277248
#define QUADS (CELLS/4)          // 69312 (exact)
#define GS_ 271                  // ceil(QUADS/256) streaming blocks
#define GT_ 16                   // target blocks, one per image
#define IGNORE_THRES_ 0.5f
#define EPS_BCE_ 1e-7f

__device__ __forceinline__ float sigmoidf_(float z) { return 1.0f / (1.0f + expf(-z)); }
__device__ __forceinline__ float smooth_l1_(float d) {
    d = fabsf(d);
    return (d < 1.0f) ? 0.5f * d * d : d - 0.5f;
}
__device__ __forceinline__ float noobj_term_(float z) {
    float pc = sigmoidf_(z);
    pc = fminf(fmaxf(pc, EPS_BCE_), 1.0f - EPS_BCE_);
    return -logf(1.0f - pc);
}

// ---------------------------------------------------------------------------
// Kernel A: GS_+GT_ blocks x 256 threads, block-specialized.
//   blocks [0,GS_): one quad (4 cells, 80 B contiguous) per thread via
//                   4x float4 loads; unconditional noobj BCE partial -> pn
//   blocks [GS_,GS_+GT_): image b = blk-GS_; 4 waves x 8 targets each:
//     wave-parallel class rows, last-write-wins winners, flagged-cell dedup
//     -> per-image acc[10] in iacc
// iacc per image: [0..3]=lx,ly,lw,lh [4]=obj [5]=ce [6]=nM [7]=ncor
//                 [8]=sub_term [9]=sub_count
// ---------------------------------------------------------------------------
__global__ __launch_bounds__(256) void kmain(
    const float* __restrict__ xreg, const float* __restrict__ xcls,
    const float* __restrict__ tgt, const float* __restrict__ anch,
    float* __restrict__ pn, float* __restrict__ iacc)
{
    const int blk = blockIdx.x, tid = threadIdx.x;
    const int lane = tid & 63, wv = tid >> 6;

    if (blk < GS_) {
        // ---- streaming noobj total: quad q = cells 4q..4q+3 ----
        int q = blk * 256 + tid;
        float s = 0.0f;
        if (q < QUADS) {
            const float4* p = (const float4*)(xreg + (size_t)q * 20);
            float4 v1 = p[1];   // floats 4..7   -> ch4 of cell0 = v1.x
            float4 v2 = p[2];   // floats 8..11  -> ch4 of cell1 = v2.y (idx 9)
            float4 v3 = p[3];   // floats 12..15 -> ch4 of cell2 = v3.z (idx 14)
            float4 v4 = p[4];   // floats 16..19 -> ch4 of cell3 = v4.w (idx 19)
            s = noobj_term_(v1.x) + noobj_term_(v2.y)
              + noobj_term_(v3.z) + noobj_term_(v4.w);
        }
        #pragma unroll
        for (int off = 32; off > 0; off >>= 1) s += __shfl_down(s, off, 64);
        __shared__ float sw[4];
        if (lane == 0) sw[wv] = s;
        __syncthreads();
        if (tid == 0) pn[blk] = sw[0] + sw[1] + sw[2] + sw[3];
        return;
    }

    // ---- target block for image b ----
    const int b = blk - GS_;
    __shared__ int s_key[T_];
    __shared__ int s_cell[T_ * A_];
    __shared__ unsigned char s_flag[T_ * A_];
    __shared__ float s_red[4 * 10];

    const float aw0 = anch[0], ah0 = anch[1];
    const float aw1 = anch[2], ah1 = anch[3];
    const float aw2 = anch[4], ah2 = anch[5];

    // phase 1: per-target keys + flagged (anchor,cell) pairs
    if (tid < T_) {
        const float* tp = tgt + (size_t)(b * T_ + tid) * 5;
        float gx = tp[0] * (float)W_, gy = tp[1] * (float)H_;
        float gw = tp[2] * (float)W_, gh = tp[3] * (float)H_;
        int gi = min(max((int)floorf(gx), 0), W_ - 1);
        int gj = min(max((int)floorf(gy), 0), H_ - 1);
        float area = gw * gh;
        float i0 = fminf(gw, aw0) * fminf(gh, ah0);
        float iou0 = i0 / (area + aw0 * ah0 - i0 + 1e-16f);
        float i1 = fminf(gw, aw1) * fminf(gh, ah1);
        float iou1 = i1 / (area + aw1 * ah1 - i1 + 1e-16f);
        float i2 = fminf(gw, aw2) * fminf(gh, ah2);
        float iou2 = i2 / (area + aw2 * ah2 - i2 + 1e-16f);
        int best = 0; float bi = iou0;
        if (iou1 > bi) { best = 1; bi = iou1; }
        if (iou2 > bi) { best = 2; bi = iou2; }
        s_key[tid] = (best * H_ + gj) * W_ + gi;
        float ious[3] = { iou0, iou1, iou2 };
        #pragma unroll
        for (int a = 0; a < A_; ++a) {
            s_cell[tid * A_ + a] = (((b * A_ + a) * H_ + gj) * W_ + gi);
            s_flag[tid * A_ + a] = (a == best || ious[a] > IGNORE_THRES_) ? 1 : 0;
        }
    }
    __syncthreads();

    // phase 2: dedup flagged cells, gather subtraction terms
    float sub_t = 0.0f, sub_c = 0.0f;
    if (tid < T_ * A_ && s_flag[tid]) {
        int c = s_cell[tid];
        bool first = true;
        for (int q = 0; q < tid; ++q)
            if (s_flag[q] && s_cell[q] == c) { first = false; break; }
        if (first) {
            sub_t = noobj_term_(xreg[(size_t)c * 5 + 4]);
            sub_c = 1.0f;
        }
    }

    // phase 3: wave wv handles targets lt = wv*8 .. wv*8+7
    float alx = 0, aly = 0, alw = 0, alh = 0, aobj = 0, ace = 0, anm = 0, anc = 0;
    for (int k = 0; k < 8; ++k) {
        const int lt = wv * 8 + k;
        const float* tp = tgt + (size_t)(b * T_ + lt) * 5;
        float gx = tp[0] * (float)W_, gy = tp[1] * (float)H_;
        float gw = tp[2] * (float)W_, gh = tp[3] * (float)H_;
        int cls = (int)tp[4];
        int gi = min(max((int)floorf(gx), 0), W_ - 1);
        int gj = min(max((int)floorf(gy), 0), H_ - 1);
        float area = gw * gh;
        float i0 = fminf(gw, aw0) * fminf(gh, ah0);
        float iou0 = i0 / (area + aw0 * ah0 - i0 + 1e-16f);
        float i1 = fminf(gw, aw1) * fminf(gh, ah1);
        float iou1 = i1 / (area + aw1 * ah1 - i1 + 1e-16f);
        float i2 = fminf(gw, aw2) * fminf(gh, ah2);
        float iou2 = i2 / (area + aw2 * ah2 - i2 + 1e-16f);
        int best = 0; float bi = iou0;
        if (iou1 > bi) { best = 1; bi = iou1; }
        if (iou2 > bi) { best = 2; bi = iou2; }

        int cell = ((b * A_ + best) * H_ + gj) * W_ + gi;
        const float* rp = xreg + (size_t)cell * 5;
        float rc = rp[4];

        // wave-parallel class row: lane l holds classes l and 64+l
        const float* cp = xcls + (size_t)cell * C_;
        float v1 = cp[lane];
        float v2 = (lane < 16) ? cp[64 + lane] : -INFINITY;
        float bv; int bidx;
        if (v2 > v1) { bv = v2; bidx = 64 + lane; }
        else         { bv = v1; bidx = lane; }
        #pragma unroll
        for (int off = 1; off < 64; off <<= 1) {
            float ov = __shfl_xor(bv, off, 64);
            int   oi = __shfl_xor(bidx, off, 64);
            if (ov > bv || (ov == bv && oi < bidx)) { bv = ov; bidx = oi; }
        }
        float m = bv;
        float e = expf(v1 - m) + ((lane < 16) ? expf(v2 - m) : 0.0f);
        #pragma unroll
        for (int off = 1; off < 64; off <<= 1) e += __shfl_xor(e, off, 64);
        float lse = m + logf(e);
        float cpval = (cls < 64) ? __shfl(v1, cls, 64) : __shfl(v2, cls - 64, 64);

        // last-write-wins winner within the image
        bool winner = true;
        int mykey = s_key[lt];
        for (int u = lt + 1; u < T_; ++u)
            if (s_key[u] == mykey) { winner = false; break; }

        if (lane == 0) {
            if (bidx == cls && rc > 0.0f) anc += 1.0f;  // sigmoid(rc)>0.5
            if (winner) {
                float rx = rp[0], ry = rp[1], rw = rp[2], rh = rp[3];
                float aw = (best == 0) ? aw0 : ((best == 1) ? aw1 : aw2);
                float ah = (best == 0) ? ah0 : ((best == 1) ? ah1 : ah2);
                alx += smooth_l1_(sigmoidf_(rx) - (gx - (float)gi));
                aly += smooth_l1_(sigmoidf_(ry) - (gy - (float)gj));
                alw += smooth_l1_(rw - logf(gw / aw + 1e-16f));
                alh += smooth_l1_(rh - logf(gh / ah + 1e-16f));
                float pc = sigmoidf_(rc);
                pc = fminf(fmaxf(pc, EPS_BCE_), 1.0f - EPS_BCE_);
                aobj += -logf(pc);
                ace += lse - cpval;
                anm += 1.0f;
            }
        }
    }

    // block reduce 10 quantities (deterministic: wave tree + fixed wave order)
    float vals[10] = { alx, aly, alw, alh, aobj, ace, anm, anc, sub_t, sub_c };
    #pragma unroll
    for (int q = 0; q < 10; ++q) {
        float v = vals[q];
        #pragma unroll
        for (int off = 32; off > 0; off >>= 1) v += __shfl_down(v, off, 64);
        vals[q] = v;
    }
    if (lane == 0) {
        #pragma unroll
        for (int q = 0; q < 10; ++q) s_red[wv * 10 + q] = vals[q];
    }
    __syncthreads();
    if (tid == 0) {
        #pragma unroll
        for (int q = 0; q < 10; ++q) {
            float s = 0.0f;
            for (int w2 = 0; w2 < 4; ++w2) s += s_red[w2 * 10 + q];
            iacc[b * 10 + q] = s;
        }
    }
}

// ---------------------------------------------------------------------------
// Kernel B: 1 block, 256 threads — deterministic final combine.
// ---------------------------------------------------------------------------
__global__ __launch_bounds__(256) void kfinal(
    const float* __restrict__ pn, const float* __restrict__ iacc,
    float* __restrict__ out)
{
    const int tid = threadIdx.x;
    const int lane = tid & 63, wv = tid >> 6;

    float s = (tid < GS_) ? pn[tid] : 0.0f;
    if (tid < GS_ - 256) s += pn[256 + tid];
    #pragma unroll
    for (int off = 32; off > 0; off >>= 1) s += __shfl_down(s, off, 64);
    __shared__ float sw[4];
    __shared__ float sa[10];
    if (lane == 0) sw[wv] = s;

    // wave 0 reduces the 16x10 iacc
    if (wv == 0) {
        #pragma unroll
        for (int q = 0; q < 10; ++q) {
            float v = (lane < GT_) ? iacc[lane * 10 + q] : 0.0f;
            #pragma unroll
            for (int off = 1; off < 16; off <<= 1) v += __shfl_xor(v, off, 64);
            if (lane == 0) sa[q] = v;
        }
    }
    __syncthreads();

    if (tid == 0) {
        float total = sw[0] + sw[1] + sw[2] + sw[3];
        float noobj_sum = total - sa[8];
        float nF = fmaxf((float)CELLS - sa[9], 1.0f);
        float nM = fmaxf(sa[6], 1.0f);
        float lx = sa[0] / nM, ly = sa[1] / nM;
        float lw = sa[2] / nM, lh = sa[3] / nM;
        float lconf = noobj_sum / nF + sa[4] / nM;
        float lcls = sa[5] / nM;
        float coord = lx + ly + lw + lh;
        out[0] = coord + lconf + lcls;
        out[1] = coord;
        out[2] = lconf;
        out[3] = lcls;
        out[4] = sa[7];  // n_correct (float32 buffer)
    }
}

extern "C" void kernel_launch(void* const* d_in, const int* in_sizes, int n_in,
                              void* d_out, int out_size, void* d_ws, size_t ws_size,
                              hipStream_t stream) {
    const float* xreg = (const float*)d_in[0];
    const float* xcls = (const float*)d_in[1];
    const float* tgt  = (const float*)d_in[2];
    const float* anch = (const float*)d_in[3];
    float* out = (float*)d_out;

    char* ws = (char*)d_ws;
    float* pn   = (float*)ws;                 // GS_ floats
    float* iacc = (float*)(ws + 2048);        // GT_*10 floats

    kmain<<<GS_ + GT_, 256, 0, stream>>>(xreg, xcls, tgt, anch, pn, iacc);
    kfinal<<<1, 256, 0, stream>>>(pn, iacc, out);
}

// Round 5
// 25.069 us; speedup vs baseline: 1.9466x; 1.9235x over previous
//
#include <hip/hip_runtime.h>
#include <math.h>

// Problem constants (from setup_inputs)
#define B_  16
#define A_  3
#define H_  76
#define W_  76
#define C_  80
#define T_  32
#define CELLS (B_*A_*H_*W_)      // 277248
#define QUADS (CELLS/4)          // 69312 (exact)
#define GS_ 271                  // ceil(QUADS/256) streaming blocks
#define GT_ (B_*8)               // 128 target blocks: 8 per image, 1 target/wave
#define IGNORE_THRES_ 0.5f
#define EPS_BCE_ 1e-7f

__device__ __forceinline__ float sigmoidf_(float z) { return 1.0f / (1.0f + expf(-z)); }
__device__ __forceinline__ float smooth_l1_(float d) {
    d = fabsf(d);
    return (d < 1.0f) ? 0.5f * d * d : d - 0.5f;
}
__device__ __forceinline__ float noobj_term_(float z) {
    float pc = sigmoidf_(z);
    pc = fminf(fmaxf(pc, EPS_BCE_), 1.0f - EPS_BCE_);
    return -logf(1.0f - pc);
}

// ---------------------------------------------------------------------------
// Kernel A: GS_+GT_ blocks x 256 threads, block-specialized.
//   blocks [0,GS_): one quad (4 cells, 80 B) per thread via float4 loads;
//                   unconditional noobj BCE partial -> pn[blk]
//   blocks [GS_,GS_+GT_): g = blk-GS_; image b = g>>3; 4 waves, each wave
//     owns ONE target lt = (g&7)*4 + wv. Wave-parallel class row, ballot
//     winner check (no serial loops). Block (g&7)==0 also dedups the
//     image's flagged cells for the noobj subtraction.
// part[g][10]: [0..3]=lx,ly,lw,lh [4]=obj [5]=ce [6]=nM [7]=ncor
//              [8]=sub_term [9]=sub_count
// ---------------------------------------------------------------------------
__global__ __launch_bounds__(256) void kmain(
    const float* __restrict__ xreg, const float* __restrict__ xcls,
    const float* __restrict__ tgt, const float* __restrict__ anch,
    float* __restrict__ pn, float* __restrict__ part)
{
    const int blk = blockIdx.x, tid = threadIdx.x;
    const int lane = tid & 63, wv = tid >> 6;

    if (blk < GS_) {
        // ---- streaming noobj total: quad q = cells 4q..4q+3 ----
        int q = blk * 256 + tid;
        float s = 0.0f;
        if (q < QUADS) {
            const float4* p = (const float4*)(xreg + (size_t)q * 20);
            float4 v1 = p[1];   // ch4 of cell0 = v1.x (flat idx 4)
            float4 v2 = p[2];   // ch4 of cell1 = v2.y (flat idx 9)
            float4 v3 = p[3];   // ch4 of cell2 = v3.z (flat idx 14)
            float4 v4 = p[4];   // ch4 of cell3 = v4.w (flat idx 19)
            s = noobj_term_(v1.x) + noobj_term_(v2.y)
              + noobj_term_(v3.z) + noobj_term_(v4.w);
        }
        #pragma unroll
        for (int off = 32; off > 0; off >>= 1) s += __shfl_down(s, off, 64);
        __shared__ float sw[4];
        if (lane == 0) sw[wv] = s;
        __syncthreads();
        if (tid == 0) pn[blk] = sw[0] + sw[1] + sw[2] + sw[3];
        return;
    }

    // ---- target block ----
    const int g = blk - GS_;
    const int b = g >> 3;
    const int lt = (g & 7) * 4 + wv;     // this wave's target within image

    __shared__ int s_key[T_];
    __shared__ int s_cell[T_ * A_];
    __shared__ unsigned char s_flag[T_ * A_];
    __shared__ float s_red[4 * 10];

    const float aw0 = anch[0], ah0 = anch[1];
    const float aw1 = anch[2], ah1 = anch[3];
    const float aw2 = anch[4], ah2 = anch[5];

    // phase 1: all 32 of the image's keys (+ flagged pairs) -- redundant
    // across the image's 8 blocks, but removes any cross-block dependency
    if (tid < T_) {
        const float* tp = tgt + (size_t)(b * T_ + tid) * 5;
        float gx = tp[0] * (float)W_, gy = tp[1] * (float)H_;
        float gw = tp[2] * (float)W_, gh = tp[3] * (float)H_;
        int gi = min(max((int)floorf(gx), 0), W_ - 1);
        int gj = min(max((int)floorf(gy), 0), H_ - 1);
        float area = gw * gh;
        float i0 = fminf(gw, aw0) * fminf(gh, ah0);
        float iou0 = i0 / (area + aw0 * ah0 - i0 + 1e-16f);
        float i1 = fminf(gw, aw1) * fminf(gh, ah1);
        float iou1 = i1 / (area + aw1 * ah1 - i1 + 1e-16f);
        float i2 = fminf(gw, aw2) * fminf(gh, ah2);
        float iou2 = i2 / (area + aw2 * ah2 - i2 + 1e-16f);
        int best = 0; float bi = iou0;
        if (iou1 > bi) { best = 1; bi = iou1; }
        if (iou2 > bi) { best = 2; bi = iou2; }
        s_key[tid] = (best * H_ + gj) * W_ + gi;
        float ious[3] = { iou0, iou1, iou2 };
        #pragma unroll
        for (int a = 0; a < A_; ++a) {
            s_cell[tid * A_ + a] = (((b * A_ + a) * H_ + gj) * W_ + gi);
            s_flag[tid * A_ + a] = (a == best || ious[a] > IGNORE_THRES_) ? 1 : 0;
        }
    }
    __syncthreads();

    // phase 2 (only one block per image): dedup flagged cells -> sub terms
    float sub_t = 0.0f, sub_c = 0.0f;
    if ((g & 7) == 0 && tid < T_ * A_ && s_flag[tid]) {
        int c = s_cell[tid];
        bool first = true;
        for (int q = 0; q < tid; ++q)
            if (s_flag[q] && s_cell[q] == c) { first = false; break; }
        if (first) {
            sub_t = noobj_term_(xreg[(size_t)c * 5 + 4]);
            sub_c = 1.0f;
        }
    }

    // phase 3: this wave's single target
    const float* tp = tgt + (size_t)(b * T_ + lt) * 5;
    float gx = tp[0] * (float)W_, gy = tp[1] * (float)H_;
    float gw = tp[2] * (float)W_, gh = tp[3] * (float)H_;
    int cls = (int)tp[4];
    int gi = min(max((int)floorf(gx), 0), W_ - 1);
    int gj = min(max((int)floorf(gy), 0), H_ - 1);
    float area = gw * gh;
    float i0 = fminf(gw, aw0) * fminf(gh, ah0);
    float iou0 = i0 / (area + aw0 * ah0 - i0 + 1e-16f);
    float i1 = fminf(gw, aw1) * fminf(gh, ah1);
    float iou1 = i1 / (area + aw1 * ah1 - i1 + 1e-16f);
    float i2 = fminf(gw, aw2) * fminf(gh, ah2);
    float iou2 = i2 / (area + aw2 * ah2 - i2 + 1e-16f);
    int best = 0; float bi = iou0;
    if (iou1 > bi) { best = 1; bi = iou1; }
    if (iou2 > bi) { best = 2; bi = iou2; }

    int cell = ((b * A_ + best) * H_ + gj) * W_ + gi;
    const float* rp = xreg + (size_t)cell * 5;
    float rc = rp[4];

    // wave-parallel class row: lane l holds classes l and 64+l
    const float* cp = xcls + (size_t)cell * C_;
    float v1 = cp[lane];
    float v2 = (lane < 16) ? cp[64 + lane] : -INFINITY;
    float bv; int bidx;
    if (v2 > v1) { bv = v2; bidx = 64 + lane; }
    else         { bv = v1; bidx = lane; }
    #pragma unroll
    for (int off = 1; off < 64; off <<= 1) {
        float ov = __shfl_xor(bv, off, 64);
        int   oi = __shfl_xor(bidx, off, 64);
        if (ov > bv || (ov == bv && oi < bidx)) { bv = ov; bidx = oi; }
    }
    float m = bv;
    float e = expf(v1 - m) + ((lane < 16) ? expf(v2 - m) : 0.0f);
    #pragma unroll
    for (int off = 1; off < 64; off <<= 1) e += __shfl_xor(e, off, 64);
    float lse = m + logf(e);
    float cpval = (cls < 64) ? __shfl(v1, cls, 64) : __shfl(v2, cls - 64, 64);

    // ballot winner check: any later target (same image) with same key?
    int mykey = s_key[lt];
    int key_l = s_key[lane & (T_ - 1)];
    unsigned long long clash =
        __ballot(lane < T_ && lane > lt && key_l == mykey);
    bool winner = (clash == 0ull);

    // per-wave results (lane 0 only) -> s_red
    if (lane == 0) {
        float wlx = 0, wly = 0, wlw = 0, wlh = 0, wobj = 0, wce = 0, wm = 0;
        float wnc = (bidx == cls && rc > 0.0f) ? 1.0f : 0.0f;
        if (winner) {
            float rx = rp[0], ry = rp[1], rw = rp[2], rh = rp[3];
            float aw = (best == 0) ? aw0 : ((best == 1) ? aw1 : aw2);
            float ah = (best == 0) ? ah0 : ((best == 1) ? ah1 : ah2);
            wlx = smooth_l1_(sigmoidf_(rx) - (gx - (float)gi));
            wly = smooth_l1_(sigmoidf_(ry) - (gy - (float)gj));
            wlw = smooth_l1_(rw - logf(gw / aw + 1e-16f));
            wlh = smooth_l1_(rh - logf(gh / ah + 1e-16f));
            float pc = sigmoidf_(rc);
            pc = fminf(fmaxf(pc, EPS_BCE_), 1.0f - EPS_BCE_);
            wobj = -logf(pc);
            wce = lse - cpval;
            wm = 1.0f;
        }
        s_red[wv * 10 + 0] = wlx;  s_red[wv * 10 + 1] = wly;
        s_red[wv * 10 + 2] = wlw;  s_red[wv * 10 + 3] = wlh;
        s_red[wv * 10 + 4] = wobj; s_red[wv * 10 + 5] = wce;
        s_red[wv * 10 + 6] = wm;   s_red[wv * 10 + 7] = wnc;
    }
    // sub terms: wave-reduce (nonzero only in tid<96 of (g&7)==0 blocks)
    #pragma unroll
    for (int off = 32; off > 0; off >>= 1) {
        sub_t += __shfl_down(sub_t, off, 64);
        sub_c += __shfl_down(sub_c, off, 64);
    }
    if (lane == 0) { s_red[wv * 10 + 8] = sub_t; s_red[wv * 10 + 9] = sub_c; }
    __syncthreads();

    if (tid == 0) {
        #pragma unroll
        for (int q = 0; q < 10; ++q)
            part[g * 10 + q] = s_red[0 * 10 + q] + s_red[1 * 10 + q]
                             + s_red[2 * 10 + q] + s_red[3 * 10 + q];
    }
}

// ---------------------------------------------------------------------------
// Kernel B: 1 block, 256 threads — deterministic final combine.
// ---------------------------------------------------------------------------
__global__ __launch_bounds__(256) void kfinal(
    const float* __restrict__ pn, const float* __restrict__ part,
    float* __restrict__ out)
{
    const int tid = threadIdx.x;
    const int lane = tid & 63, wv = tid >> 6;

    float s = (tid < GS_) ? pn[tid] : 0.0f;
    if (tid < GS_ - 256) s += pn[256 + tid];
    #pragma unroll
    for (int off = 32; off > 0; off >>= 1) s += __shfl_down(s, off, 64);
    __shared__ float sw[4];
    __shared__ float sa[10];
    if (lane == 0) sw[wv] = s;

    // wave 0 reduces part[128][10] (fixed order: lane + lane+64, butterfly)
    if (wv == 0) {
        #pragma unroll
        for (int q = 0; q < 10; ++q) {
            float v = part[lane * 10 + q] + part[(64 + lane) * 10 + q];
            #pragma unroll
            for (int off = 1; off < 64; off <<= 1) v += __shfl_xor(v, off, 64);
            if (lane == 0) sa[q] = v;
        }
    }
    __syncthreads();

    if (tid == 0) {
        float total = sw[0] + sw[1] + sw[2] + sw[3];
        float noobj_sum = total - sa[8];
        float nF = fmaxf((float)CELLS - sa[9], 1.0f);
        float nM = fmaxf(sa[6], 1.0f);
        float lx = sa[0] / nM, ly = sa[1] / nM;
        float lw = sa[2] / nM, lh = sa[3] / nM;
        float lconf = noobj_sum / nF + sa[4] / nM;
        float lcls = sa[5] / nM;
        float coord = lx + ly + lw + lh;
        out[0] = coord + lconf + lcls;
        out[1] = coord;
        out[2] = lconf;
        out[3] = lcls;
        out[4] = sa[7];  // n_correct (float32 buffer)
    }
}

extern "C" void kernel_launch(void* const* d_in, const int* in_sizes, int n_in,
                              void* d_out, int out_size, void* d_ws, size_t ws_size,
                              hipStream_t stream) {
    const float* xreg = (const float*)d_in[0];
    const float* xcls = (const float*)d_in[1];
    const float* tgt  = (const float*)d_in[2];
    const float* anch = (const float*)d_in[3];
    float* out = (float*)d_out;

    char* ws = (char*)d_ws;
    float* pn   = (float*)ws;                 // GS_ floats
    float* part = (float*)(ws + 2048);        // GT_*10 floats

    kmain<<<GS_ + GT_, 256, 0, stream>>>(xreg, xcls, tgt, anch, pn, part);
    kfinal<<<1, 256, 0, stream>>>(pn, part, out);
}